// Round 8
// baseline (380.667 us; speedup 1.0000x reference)
//
#include <hip/hip_runtime.h>
#include <hip/hip_fp16.h>

#define EMB_D 64
#define SB 1024   // scan block size

// ===========================================================================
// Tier A: fp16 emb + packed (src|w) CSR, partition-major buckets.
//   cast -> histA (counts[p][v]) -> 3-phase scan -> bucketA (single coverage,
//   local-XCD cursor atomics, packed payload) -> gatherA (fp16, fused norm)
// Tier B: Round-7 fp32 pipeline (proven 335 us) if ws too small for A.
// Tier C: atomic scatter fallback.
// ===========================================================================

__device__ __forceinline__ float h15_to_float(unsigned int bits) {
    return __half2float(__ushort_as_half((unsigned short)bits));
}

// --- Tier A: cast emb fp32 -> fp16 ---------------------------------------
__global__ void cast_emb_kernel(const float2* __restrict__ in,
                                __half2* __restrict__ out, int n2) {
    int i = blockIdx.x * blockDim.x + threadIdx.x;
    int st = gridDim.x * blockDim.x;
    for (; i < n2; i += st)
        out[i] = __float22half2_rn(in[i]);
}

// --- Tier A: histogram over (partition, node) ----------------------------
__global__ void histA_kernel(const int* __restrict__ dst, int* __restrict__ counts,
                             int E, int ppe, int N) {
    int i = blockIdx.x * blockDim.x + threadIdx.x;
    int stride = gridDim.x * blockDim.x;
    for (; i < E; i += stride) {
        int p = i / ppe;
        atomicAdd(&counts[p * N + dst[i]], 1);
    }
}

// --- shared 3-phase scan (length M) --------------------------------------
__global__ void scan_reduce(const int* __restrict__ counts,
                            int* __restrict__ partial, int M) {
    __shared__ int wsum[16];
    const int tid = threadIdx.x, lane = tid & 63, wid = tid >> 6;
    int i = blockIdx.x * SB + tid;
    int v = (i < M) ? counts[i] : 0;
    #pragma unroll
    for (int off = 32; off > 0; off >>= 1)
        v += __shfl_xor(v, off, 64);
    if (lane == 0) wsum[wid] = v;
    __syncthreads();
    if (tid == 0) {
        int s = 0;
        #pragma unroll
        for (int k = 0; k < 16; ++k) s += wsum[k];
        partial[blockIdx.x] = s;
    }
}

__global__ void scan_partials(const int* __restrict__ partial,
                              int* __restrict__ blockoff,
                              int* __restrict__ offsets, int numB, int M) {
    __shared__ int wsum[16];
    __shared__ int wpre[16];
    const int tid = threadIdx.x, lane = tid & 63, wid = tid >> 6;
    int v = (tid < numB) ? partial[tid] : 0;
    int x = v;
    #pragma unroll
    for (int off = 1; off < 64; off <<= 1) {
        int t = __shfl_up(x, off, 64);
        if (lane >= off) x += t;
    }
    if (lane == 63) wsum[wid] = x;
    __syncthreads();
    if (wid == 0) {
        int s = (lane < 16) ? wsum[lane] : 0;
        #pragma unroll
        for (int off = 1; off < 16; off <<= 1) {
            int t = __shfl_up(s, off, 64);
            if (lane >= off) s += t;
        }
        if (lane < 16) wpre[lane] = s;
    }
    __syncthreads();
    int excl = ((wid > 0) ? wpre[wid - 1] : 0) + (x - v);
    if (tid < numB) blockoff[tid] = excl;
    if (tid == 0) offsets[M] = wpre[15];   // grand total = E
}

// writes offsets[i]; optionally mirrors into cursors (tier A)
__global__ void scan_apply(const int* __restrict__ counts,
                           const int* __restrict__ blockoff,
                           int* __restrict__ offsets,
                           int* __restrict__ cursors, int M) {
    __shared__ int wsum[16];
    __shared__ int wpre[16];
    const int tid = threadIdx.x, lane = tid & 63, wid = tid >> 6;
    int i = blockIdx.x * SB + tid;
    int v = (i < M) ? counts[i] : 0;
    int x = v;
    #pragma unroll
    for (int off = 1; off < 64; off <<= 1) {
        int t = __shfl_up(x, off, 64);
        if (lane >= off) x += t;
    }
    if (lane == 63) wsum[wid] = x;
    __syncthreads();
    if (wid == 0) {
        int s = (lane < 16) ? wsum[lane] : 0;
        #pragma unroll
        for (int off = 1; off < 16; off <<= 1) {
            int t = __shfl_up(s, off, 64);
            if (lane >= off) s += t;
        }
        if (lane < 16) wpre[lane] = s;
    }
    __syncthreads();
    int excl = blockoff[blockIdx.x] + ((wid > 0) ? wpre[wid - 1] : 0) + (x - v);
    if (i < M) {
        offsets[i] = excl;
        if (cursors) cursors[i] = excl;
    }
}

// --- Tier A: single-coverage bucket, packed payload ----------------------
// Group g = blockIdx&7 owns partition g's index range. Its store region
// [offsets[g*N] ..) is contiguous -> one XCD (heuristic %8) owns those lines.
// Cursor rows cursors[g*N..] touched only by group g -> local-XCD atomics.
__global__ void bucketA_kernel(const int* __restrict__ src,
                               const int* __restrict__ dst,
                               const float* __restrict__ w,
                               int* __restrict__ cursors,
                               unsigned int* __restrict__ packed,
                               int E, int ppe, int N) {
    int g = blockIdx.x & 7;
    int b = blockIdx.x >> 3;
    int lo = g * ppe;
    int hi = min(lo + ppe, E);
    int stride = (gridDim.x >> 3) * blockDim.x;
    for (int i = lo + b * blockDim.x + threadIdx.x; i < hi; i += stride) {
        int v = dst[i];
        int slot = atomicAdd(&cursors[g * N + v], 1);
        unsigned int wb = __half_as_ushort(__float2half_rn(w[i]));
        packed[slot] = ((unsigned int)src[i] << 15) | (wb & 0x7FFFu);
    }
}

// --- Tier A: fp16 gather + fused L2 normalize ----------------------------
// One wave per node; half-waves process 2 edges/iter. Lane hl owns dims
// (2hl, 2hl+1). Per edge: 1 sequential packed u32 + 1 fp16 row half-read.
__global__ __launch_bounds__(256) void gatherA_kernel(
        const __half2* __restrict__ emb16,
        const int* __restrict__ offsets,   // [8N+1], partition-major
        const unsigned int* __restrict__ packed,
        float* __restrict__ out, int N) {
    int node = blockIdx.x * 4 + (threadIdx.x >> 6);
    int lane = threadIdx.x & 63;
    if (node >= N) return;
    int half = lane >> 5;
    int hl = lane & 31;

    int sbeg[8], send[8];
    #pragma unroll
    for (int p = 0; p < 8; ++p) {
        sbeg[p] = offsets[p * N + node];
        send[p] = offsets[p * N + node + 1];
    }

    float a0 = 0.f, a1 = 0.f;
    #pragma unroll
    for (int p = 0; p < 8; ++p) {
        for (int j = sbeg[p]; j < send[p]; j += 2) {
            int idx = j + half;
            if (idx < send[p]) {
                unsigned int pk = packed[idx];
                float wt = h15_to_float(pk & 0x7FFFu);
                float2 xv = __half22float2(emb16[(size_t)(pk >> 15) * 32 + hl]);
                a0 = fmaf(xv.x, wt, a0);
                a1 = fmaf(xv.y, wt, a1);
            }
        }
    }
    // merge the two half-wave partials (same dims, different edges)
    a0 += __shfl_xor(a0, 32, 64);
    a1 += __shfl_xor(a1, 32, 64);
    float ss = a0 * a0 + a1 * a1;
    #pragma unroll
    for (int off = 16; off > 0; off >>= 1)
        ss += __shfl_xor(ss, off, 64);
    float scale = 1.0f / fmaxf(sqrtf(ss), 1e-12f);
    if (half == 0) {
        float2 o = make_float2(a0 * scale, a1 * scale);
        reinterpret_cast<float2*>(out + (size_t)node * EMB_D)[hl] = o;
    }
}

// ===========================================================================
// Tier B: Round-7 pipeline (fp32, eids CSR) — proven 335 us.
// ===========================================================================
__global__ void hist_kernel(const int* __restrict__ dst, int* __restrict__ counts,
                            int* __restrict__ ranks, int E) {
    int i = blockIdx.x * blockDim.x + threadIdx.x;
    int stride = gridDim.x * blockDim.x;
    for (; i < E; i += stride)
        ranks[i] = atomicAdd(&counts[dst[i]], 1);
}

__global__ void bucket_kernel(const int* __restrict__ dst,
                              const int* __restrict__ ranks,
                              const int* __restrict__ offsets,
                              int* __restrict__ eids, int E, int span) {
    int xcd = blockIdx.x & 7;
    int g   = blockIdx.x >> 3;
    int lo = xcd * span;
    int hi = lo + span;
    int stride = (gridDim.x >> 3) * blockDim.x;
    for (int i = g * blockDim.x + threadIdx.x; i < E; i += stride) {
        int v = dst[i];
        if (v >= lo && v < hi)
            eids[offsets[v] + ranks[i]] = i;
    }
}

__global__ __launch_bounds__(256) void gather_norm_kernel(
        const float* __restrict__ emb,
        const int* __restrict__ offsets,
        const int* __restrict__ eids,
        const int* __restrict__ src,
        const float* __restrict__ w,
        float* __restrict__ out, int N) {
    int node = blockIdx.x * 4 + (threadIdx.x >> 6);
    int lane = threadIdx.x & 63;
    if (node >= N) return;

    int beg = offsets[node];
    int end = offsets[node + 1];

    float a0 = 0.f, a1 = 0.f, a2 = 0.f, a3 = 0.f;
    int j = beg;
    for (; j + 4 <= end; j += 4) {
        int e0 = eids[j + 0], e1 = eids[j + 1];
        int e2 = eids[j + 2], e3 = eids[j + 3];
        int s0 = src[e0], s1 = src[e1], s2 = src[e2], s3 = src[e3];
        float w0 = w[e0], w1 = w[e1], w2 = w[e2], w3 = w[e3];
        a0 = fmaf(emb[(size_t)s0 * EMB_D + lane], w0, a0);
        a1 = fmaf(emb[(size_t)s1 * EMB_D + lane], w1, a1);
        a2 = fmaf(emb[(size_t)s2 * EMB_D + lane], w2, a2);
        a3 = fmaf(emb[(size_t)s3 * EMB_D + lane], w3, a3);
    }
    for (; j < end; ++j) {
        int e = eids[j];
        a0 = fmaf(emb[(size_t)src[e] * EMB_D + lane], w[e], a0);
    }
    float acc = (a0 + a1) + (a2 + a3);

    float ss = acc * acc;
    #pragma unroll
    for (int off = 32; off > 0; off >>= 1)
        ss += __shfl_xor(ss, off, 64);
    float scale = 1.0f / fmaxf(sqrtf(ss), 1e-12f);
    out[(size_t)node * EMB_D + lane] = acc * scale;
}

// ===========================================================================
// Tier C: atomic scatter fallback.
// ===========================================================================
__global__ void lightgcn_scatter(const float* __restrict__ emb,
                                 const float* __restrict__ w,
                                 const int* __restrict__ src,
                                 const int* __restrict__ dst,
                                 float* __restrict__ h, int E) {
    long long t = (long long)blockIdx.x * blockDim.x + threadIdx.x;
    int e = (int)(t >> 4);
    int d = (int)(t & 15) << 2;
    if (e >= E) return;
    int s = src[e]; int v = dst[e]; float wt = w[e];
    const float4 m = *reinterpret_cast<const float4*>(emb + (size_t)s * EMB_D + d);
    float* o = h + (size_t)v * EMB_D + d;
    unsafeAtomicAdd(o + 0, m.x * wt);
    unsafeAtomicAdd(o + 1, m.y * wt);
    unsafeAtomicAdd(o + 2, m.z * wt);
    unsafeAtomicAdd(o + 3, m.w * wt);
}

__global__ void lightgcn_normalize(float* __restrict__ h, int N) {
    int row = blockIdx.x * (blockDim.x >> 6) + (threadIdx.x >> 6);
    int lane = threadIdx.x & 63;
    if (row >= N) return;
    float x = h[(size_t)row * EMB_D + lane];
    float ss = x * x;
    #pragma unroll
    for (int off = 32; off > 0; off >>= 1)
        ss += __shfl_xor(ss, off, 64);
    h[(size_t)row * EMB_D + lane] = x / fmaxf(sqrtf(ss), 1e-12f);
}

extern "C" void kernel_launch(void* const* d_in, const int* in_sizes, int n_in,
                              void* d_out, int out_size, void* d_ws, size_t ws_size,
                              hipStream_t stream) {
    const float* emb = (const float*)d_in[0];   // [N, 64] fp32
    const float* w   = (const float*)d_in[1];   // [E] fp32
    const int*   src = (const int*)d_in[2];     // [E] int32
    const int*   dst = (const int*)d_in[3];     // [E] int32
    float* out = (float*)d_out;

    const int N = in_sizes[0] / EMB_D;
    const int E = in_sizes[1];
    const int block = 256;

    // ---- Tier A workspace ----
    const int M = 8 * N;
    const int numBA = (M + SB - 1) / SB;
    size_t intsA = (size_t)3 * M + 1 + 2 * numBA + E;
    size_t embOff = (intsA * sizeof(int) + 15) & ~(size_t)15;
    size_t neededA = embOff + (size_t)N * EMB_D * sizeof(__half);

    // ---- Tier B workspace (Round 7) ----
    const int numB7 = (N + SB - 1) / SB;
    size_t needed7 = (size_t)(2 * N + 1 + 2 * numB7 + 2 * E) * sizeof(int);

    if (ws_size >= neededA && numBA <= 1024) {
        int* counts   = (int*)d_ws;
        int* offsets  = counts + M;          // M+1
        int* cursors  = offsets + M + 1;     // M
        int* partial  = cursors + M;
        int* blockoff = partial + numBA;
        unsigned int* packed = (unsigned int*)(blockoff + numBA);   // E
        __half2* emb16 = (__half2*)((char*)d_ws + embOff);

        hipMemsetAsync(counts, 0, (size_t)M * sizeof(int), stream);

        int n2 = N * (EMB_D / 2);
        cast_emb_kernel<<<(n2 + block - 1) / block, block, 0, stream>>>(
            (const float2*)emb, emb16, n2);

        const int ppe = (E + 7) / 8;
        int gridE = (E + block - 1) / block;
        histA_kernel<<<gridE, block, 0, stream>>>(dst, counts, E, ppe, N);
        scan_reduce<<<numBA, SB, 0, stream>>>(counts, partial, M);
        scan_partials<<<1, SB, 0, stream>>>(partial, blockoff, offsets, numBA, M);
        scan_apply<<<numBA, SB, 0, stream>>>(counts, blockoff, offsets, cursors, M);

        bucketA_kernel<<<8 * 256, block, 0, stream>>>(src, dst, w, cursors,
                                                      packed, E, ppe, N);

        int gridN = (N + 3) / 4;
        gatherA_kernel<<<gridN, 256, 0, stream>>>(emb16, offsets, packed, out, N);
    } else if (ws_size >= needed7 && numB7 <= 1024) {
        int* counts   = (int*)d_ws;
        int* offsets  = counts + N;
        int* partial  = offsets + N + 1;
        int* blockoff = partial + numB7;
        int* ranks    = blockoff + numB7;
        int* eids     = ranks + E;

        hipMemsetAsync(counts, 0, (size_t)N * sizeof(int), stream);

        int gridE = (E + block - 1) / block;
        hist_kernel<<<gridE, block, 0, stream>>>(dst, counts, ranks, E);
        scan_reduce<<<numB7, SB, 0, stream>>>(counts, partial, N);
        scan_partials<<<1, SB, 0, stream>>>(partial, blockoff, offsets, numB7, N);
        scan_apply<<<numB7, SB, 0, stream>>>(counts, blockoff, offsets, nullptr, N);

        int span = (N + 7) / 8;
        bucket_kernel<<<8 * 256, block, 0, stream>>>(dst, ranks, offsets, eids, E, span);

        int gridN = (N + 3) / 4;
        gather_norm_kernel<<<gridN, 256, 0, stream>>>(emb, offsets, eids, src, w, out, N);
    } else {
        hipMemsetAsync(d_out, 0, (size_t)out_size * sizeof(float), stream);
        long long total = (long long)E * 16;
        int grid = (int)((total + block - 1) / block);
        lightgcn_scatter<<<grid, block, 0, stream>>>(emb, w, src, dst, out, E);
        int gridN = (N + 3) / 4;
        lightgcn_normalize<<<gridN, 256, 0, stream>>>(out, N);
    }
}

// Round 9
// 376.763 us; speedup vs baseline: 1.0104x; 1.0104x over previous
//
#include <hip/hip_runtime.h>
#include <hip/hip_fp16.h>

#define EMB_D 64
#define SB 1024   // scan block size
#define NPART 4   // CSR partitions (tier A)

// ===========================================================================
// Tier A: fp16 emb + packed (src17|w15) CSR, partition-major (P=4).
//   fused cast+hist -> 3-phase scan (cursors in place) -> bucket (cursor
//   atomics, XCD-affine regions) -> gather (quarter-wave, 2-deep pipeline,
//   fused L2 norm)
// Tier B: Round-7 fp32 pipeline (proven 335 us). Tier C: atomic scatter.
// ===========================================================================

__device__ __forceinline__ float h15_to_float(unsigned int bits) {
    return __half2float(__ushort_as_half((unsigned short)bits));
}

// --- Tier A: fused cast(emb fp32->fp16) + histogram over (partition,node) --
#define CAST_BLOCKS 256
__global__ void fused_cast_hist(const float2* __restrict__ embin,
                                __half2* __restrict__ emb16, int n2,
                                const int* __restrict__ dst,
                                int* __restrict__ counts,
                                int E, int ppe, int N) {
    if (blockIdx.x < CAST_BLOCKS) {
        int i = blockIdx.x * blockDim.x + threadIdx.x;
        int st = CAST_BLOCKS * blockDim.x;
        for (; i < n2; i += st)
            emb16[i] = __float22half2_rn(embin[i]);
    } else {
        int i = (blockIdx.x - CAST_BLOCKS) * blockDim.x + threadIdx.x;
        int st = (gridDim.x - CAST_BLOCKS) * blockDim.x;
        for (; i < E; i += st) {
            int p = i / ppe;
            atomicAdd(&counts[p * N + dst[i]], 1);
        }
    }
}

// --- shared 3-phase scan (length M) --------------------------------------
__global__ void scan_reduce(const int* __restrict__ counts,
                            int* __restrict__ partial, int M) {
    __shared__ int wsum[16];
    const int tid = threadIdx.x, lane = tid & 63, wid = tid >> 6;
    int i = blockIdx.x * SB + tid;
    int v = (i < M) ? counts[i] : 0;
    #pragma unroll
    for (int off = 32; off > 0; off >>= 1)
        v += __shfl_xor(v, off, 64);
    if (lane == 0) wsum[wid] = v;
    __syncthreads();
    if (tid == 0) {
        int s = 0;
        #pragma unroll
        for (int k = 0; k < 16; ++k) s += wsum[k];
        partial[blockIdx.x] = s;
    }
}

__global__ void scan_partials(const int* __restrict__ partial,
                              int* __restrict__ blockoff,
                              int* __restrict__ offsets, int numB, int M) {
    __shared__ int wsum[16];
    __shared__ int wpre[16];
    const int tid = threadIdx.x, lane = tid & 63, wid = tid >> 6;
    int v = (tid < numB) ? partial[tid] : 0;
    int x = v;
    #pragma unroll
    for (int off = 1; off < 64; off <<= 1) {
        int t = __shfl_up(x, off, 64);
        if (lane >= off) x += t;
    }
    if (lane == 63) wsum[wid] = x;
    __syncthreads();
    if (wid == 0) {
        int s = (lane < 16) ? wsum[lane] : 0;
        #pragma unroll
        for (int off = 1; off < 16; off <<= 1) {
            int t = __shfl_up(s, off, 64);
            if (lane >= off) s += t;
        }
        if (lane < 16) wpre[lane] = s;
    }
    __syncthreads();
    int excl = ((wid > 0) ? wpre[wid - 1] : 0) + (x - v);
    if (tid < numB) blockoff[tid] = excl;
    if (tid == 0) offsets[M] = wpre[15];   // grand total = E
}

// writes offsets[i]; optionally mirrors excl into cursors (may alias counts)
__global__ void scan_apply(const int* __restrict__ counts,
                           const int* __restrict__ blockoff,
                           int* __restrict__ offsets,
                           int* __restrict__ cursors, int M) {
    __shared__ int wsum[16];
    __shared__ int wpre[16];
    const int tid = threadIdx.x, lane = tid & 63, wid = tid >> 6;
    int i = blockIdx.x * SB + tid;
    int v = (i < M) ? counts[i] : 0;
    int x = v;
    #pragma unroll
    for (int off = 1; off < 64; off <<= 1) {
        int t = __shfl_up(x, off, 64);
        if (lane >= off) x += t;
    }
    if (lane == 63) wsum[wid] = x;
    __syncthreads();
    if (wid == 0) {
        int s = (lane < 16) ? wsum[lane] : 0;
        #pragma unroll
        for (int off = 1; off < 16; off <<= 1) {
            int t = __shfl_up(s, off, 64);
            if (lane >= off) s += t;
        }
        if (lane < 16) wpre[lane] = s;
    }
    __syncthreads();
    int excl = blockoff[blockIdx.x] + ((wid > 0) ? wpre[wid - 1] : 0) + (x - v);
    if (i < M) {
        offsets[i] = excl;
        if (cursors) cursors[i] = excl;
    }
}

// --- Tier A: bucket scatter, partition regions XCD-affine ----------------
// Group g = blockIdx&3 owns edge range [g*ppe, (g+1)*ppe): its store region
// [offsets[g*N]..) is contiguous -> owned by <=2 XCDs (blockIdx%8 in {g,g+4}).
__global__ void bucketA_kernel(const int* __restrict__ src,
                               const int* __restrict__ dst,
                               const float* __restrict__ w,
                               int* __restrict__ cursors,
                               unsigned int* __restrict__ packed,
                               int E, int ppe, int N) {
    int g = blockIdx.x & 3;
    int b = blockIdx.x >> 2;
    int lo = g * ppe;
    int hi = min(lo + ppe, E);
    int stride = (gridDim.x >> 2) * blockDim.x;
    for (int i = lo + b * blockDim.x + threadIdx.x; i < hi; i += stride) {
        int v = dst[i];
        int slot = atomicAdd(&cursors[g * N + v], 1);
        unsigned int wb = __half_as_ushort(__float2half_rn(w[i]));
        packed[slot] = ((unsigned int)src[i] << 15) | (wb & 0x7FFFu);
    }
}

// --- Tier A: fp16 gather, quarter-wave per edge, 2-deep pipeline ---------
// Wave = 64 lanes: quarter q = lane>>4 processes edge j+q; lane ql = lane&15
// owns dims [4ql,4ql+4) via one 8B uint2 (= 4 halves). Invalid lanes use the
// sentinel pk=0 (row 0, weight +0) so loads stay unpredicated.
__global__ __launch_bounds__(256) void gatherA_kernel(
        const uint2* __restrict__ emb16,       // row v = 16 x uint2 (128 B)
        const int* __restrict__ offsets,       // [NPART*N+1], partition-major
        const unsigned int* __restrict__ packed,
        float* __restrict__ out, int N) {
    int node = blockIdx.x * 4 + (threadIdx.x >> 6);
    int lane = threadIdx.x & 63;
    if (node >= N) return;
    int q  = lane >> 4;
    int ql = lane & 15;

    float a0 = 0.f, a1 = 0.f, a2 = 0.f, a3 = 0.f;

    #pragma unroll
    for (int p = 0; p < NPART; ++p) {
        int beg = offsets[p * N + node];
        int end = offsets[p * N + node + 1];

        int idx0 = beg + q;
        unsigned int pk0 = (idx0 < end) ? packed[idx0] : 0u;
        uint2 r0 = emb16[(size_t)(pk0 >> 15) * 16 + ql];

        for (int j = beg; j < end; j += 4) {
            int idx1 = idx0 + 4;
            unsigned int pk1 = (idx1 < end) ? packed[idx1] : 0u;
            uint2 r1 = emb16[(size_t)(pk1 >> 15) * 16 + ql];  // next in flight

            float wt = h15_to_float(pk0 & 0x7FFFu);
            float2 x01 = __half22float2(*reinterpret_cast<__half2*>(&r0.x));
            float2 x23 = __half22float2(*reinterpret_cast<__half2*>(&r0.y));
            a0 = fmaf(x01.x, wt, a0);
            a1 = fmaf(x01.y, wt, a1);
            a2 = fmaf(x23.x, wt, a2);
            a3 = fmaf(x23.y, wt, a3);

            pk0 = pk1; r0 = r1; idx0 = idx1;
        }
    }

    // merge the 4 quarter-wave partials (same dims, different edges)
    a0 += __shfl_xor(a0, 16, 64); a0 += __shfl_xor(a0, 32, 64);
    a1 += __shfl_xor(a1, 16, 64); a1 += __shfl_xor(a1, 32, 64);
    a2 += __shfl_xor(a2, 16, 64); a2 += __shfl_xor(a2, 32, 64);
    a3 += __shfl_xor(a3, 16, 64); a3 += __shfl_xor(a3, 32, 64);

    float ss = a0 * a0 + a1 * a1 + a2 * a2 + a3 * a3;
    #pragma unroll
    for (int off = 8; off > 0; off >>= 1)
        ss += __shfl_xor(ss, off, 64);
    float scale = 1.0f / fmaxf(sqrtf(ss), 1e-12f);

    if (q == 0) {
        float4 o = make_float4(a0 * scale, a1 * scale, a2 * scale, a3 * scale);
        reinterpret_cast<float4*>(out + (size_t)node * EMB_D)[ql] = o;
    }
}

// ===========================================================================
// Tier B: Round-7 pipeline (fp32, eids CSR) — proven 335 us.
// ===========================================================================
__global__ void hist_kernel(const int* __restrict__ dst, int* __restrict__ counts,
                            int* __restrict__ ranks, int E) {
    int i = blockIdx.x * blockDim.x + threadIdx.x;
    int stride = gridDim.x * blockDim.x;
    for (; i < E; i += stride)
        ranks[i] = atomicAdd(&counts[dst[i]], 1);
}

__global__ void bucket_kernel(const int* __restrict__ dst,
                              const int* __restrict__ ranks,
                              const int* __restrict__ offsets,
                              int* __restrict__ eids, int E, int span) {
    int xcd = blockIdx.x & 7;
    int g   = blockIdx.x >> 3;
    int lo = xcd * span;
    int hi = lo + span;
    int stride = (gridDim.x >> 3) * blockDim.x;
    for (int i = g * blockDim.x + threadIdx.x; i < E; i += stride) {
        int v = dst[i];
        if (v >= lo && v < hi)
            eids[offsets[v] + ranks[i]] = i;
    }
}

__global__ __launch_bounds__(256) void gather_norm_kernel(
        const float* __restrict__ emb,
        const int* __restrict__ offsets,
        const int* __restrict__ eids,
        const int* __restrict__ src,
        const float* __restrict__ w,
        float* __restrict__ out, int N) {
    int node = blockIdx.x * 4 + (threadIdx.x >> 6);
    int lane = threadIdx.x & 63;
    if (node >= N) return;

    int beg = offsets[node];
    int end = offsets[node + 1];

    float a0 = 0.f, a1 = 0.f, a2 = 0.f, a3 = 0.f;
    int j = beg;
    for (; j + 4 <= end; j += 4) {
        int e0 = eids[j + 0], e1 = eids[j + 1];
        int e2 = eids[j + 2], e3 = eids[j + 3];
        int s0 = src[e0], s1 = src[e1], s2 = src[e2], s3 = src[e3];
        float w0 = w[e0], w1 = w[e1], w2 = w[e2], w3 = w[e3];
        a0 = fmaf(emb[(size_t)s0 * EMB_D + lane], w0, a0);
        a1 = fmaf(emb[(size_t)s1 * EMB_D + lane], w1, a1);
        a2 = fmaf(emb[(size_t)s2 * EMB_D + lane], w2, a2);
        a3 = fmaf(emb[(size_t)s3 * EMB_D + lane], w3, a3);
    }
    for (; j < end; ++j) {
        int e = eids[j];
        a0 = fmaf(emb[(size_t)src[e] * EMB_D + lane], w[e], a0);
    }
    float acc = (a0 + a1) + (a2 + a3);

    float ss = acc * acc;
    #pragma unroll
    for (int off = 32; off > 0; off >>= 1)
        ss += __shfl_xor(ss, off, 64);
    float scale = 1.0f / fmaxf(sqrtf(ss), 1e-12f);
    out[(size_t)node * EMB_D + lane] = acc * scale;
}

// ===========================================================================
// Tier C: atomic scatter fallback.
// ===========================================================================
__global__ void lightgcn_scatter(const float* __restrict__ emb,
                                 const float* __restrict__ w,
                                 const int* __restrict__ src,
                                 const int* __restrict__ dst,
                                 float* __restrict__ h, int E) {
    long long t = (long long)blockIdx.x * blockDim.x + threadIdx.x;
    int e = (int)(t >> 4);
    int d = (int)(t & 15) << 2;
    if (e >= E) return;
    int s = src[e]; int v = dst[e]; float wt = w[e];
    const float4 m = *reinterpret_cast<const float4*>(emb + (size_t)s * EMB_D + d);
    float* o = h + (size_t)v * EMB_D + d;
    unsafeAtomicAdd(o + 0, m.x * wt);
    unsafeAtomicAdd(o + 1, m.y * wt);
    unsafeAtomicAdd(o + 2, m.z * wt);
    unsafeAtomicAdd(o + 3, m.w * wt);
}

__global__ void lightgcn_normalize(float* __restrict__ h, int N) {
    int row = blockIdx.x * (blockDim.x >> 6) + (threadIdx.x >> 6);
    int lane = threadIdx.x & 63;
    if (row >= N) return;
    float x = h[(size_t)row * EMB_D + lane];
    float ss = x * x;
    #pragma unroll
    for (int off = 32; off > 0; off >>= 1)
        ss += __shfl_xor(ss, off, 64);
    h[(size_t)row * EMB_D + lane] = x / fmaxf(sqrtf(ss), 1e-12f);
}

extern "C" void kernel_launch(void* const* d_in, const int* in_sizes, int n_in,
                              void* d_out, int out_size, void* d_ws, size_t ws_size,
                              hipStream_t stream) {
    const float* emb = (const float*)d_in[0];   // [N, 64] fp32
    const float* w   = (const float*)d_in[1];   // [E] fp32
    const int*   src = (const int*)d_in[2];     // [E] int32
    const int*   dst = (const int*)d_in[3];     // [E] int32
    float* out = (float*)d_out;

    const int N = in_sizes[0] / EMB_D;
    const int E = in_sizes[1];
    const int block = 256;

    // ---- Tier A workspace: counts[M] | offsets[M+1] | partial | blockoff |
    //      packed[E] | pad16 | emb16[N*64 halves] ----
    const int M = NPART * N;
    const int numBA = (M + SB - 1) / SB;
    size_t intsA = (size_t)(2 * M + 1 + 2 * numBA) + E;
    size_t embOff = (intsA * sizeof(int) + 15) & ~(size_t)15;
    size_t neededA = embOff + (size_t)N * EMB_D * sizeof(__half);

    // ---- Tier B workspace ----
    const int numB7 = (N + SB - 1) / SB;
    size_t needed7 = (size_t)(2 * N + 1 + 2 * numB7 + 2 * E) * sizeof(int);

    if (ws_size >= neededA && numBA <= 1024) {
        int* counts   = (int*)d_ws;          // M (becomes cursors after scan)
        int* offsets  = counts + M;          // M+1
        int* partial  = offsets + M + 1;
        int* blockoff = partial + numBA;
        unsigned int* packed = (unsigned int*)(blockoff + numBA);   // E
        __half2* emb16 = (__half2*)((char*)d_ws + embOff);

        hipMemsetAsync(counts, 0, (size_t)M * sizeof(int), stream);

        int n2 = N * (EMB_D / 2);
        const int ppe = (E + NPART - 1) / NPART;
        fused_cast_hist<<<CAST_BLOCKS + 1024, block, 0, stream>>>(
            (const float2*)emb, emb16, n2, dst, counts, E, ppe, N);

        scan_reduce<<<numBA, SB, 0, stream>>>(counts, partial, M);
        scan_partials<<<1, SB, 0, stream>>>(partial, blockoff, offsets, numBA, M);
        // mirrors exclusive sums into counts (in place) as bucket cursors
        scan_apply<<<numBA, SB, 0, stream>>>(counts, blockoff, offsets, counts, M);

        bucketA_kernel<<<4 * 512, block, 0, stream>>>(src, dst, w, counts,
                                                      packed, E, ppe, N);

        int gridN = (N + 3) / 4;
        gatherA_kernel<<<gridN, 256, 0, stream>>>((const uint2*)emb16, offsets,
                                                  packed, out, N);
    } else if (ws_size >= needed7 && numB7 <= 1024) {
        int* counts   = (int*)d_ws;
        int* offsets  = counts + N;
        int* partial  = offsets + N + 1;
        int* blockoff = partial + numB7;
        int* ranks    = blockoff + numB7;
        int* eids     = ranks + E;

        hipMemsetAsync(counts, 0, (size_t)N * sizeof(int), stream);

        int gridE = (E + block - 1) / block;
        hist_kernel<<<gridE, block, 0, stream>>>(dst, counts, ranks, E);
        scan_reduce<<<numB7, SB, 0, stream>>>(counts, partial, N);
        scan_partials<<<1, SB, 0, stream>>>(partial, blockoff, offsets, numB7, N);
        scan_apply<<<numB7, SB, 0, stream>>>(counts, blockoff, offsets, nullptr, N);

        int span = (N + 7) / 8;
        bucket_kernel<<<8 * 256, block, 0, stream>>>(dst, ranks, offsets, eids, E, span);

        int gridN = (N + 3) / 4;
        gather_norm_kernel<<<gridN, 256, 0, stream>>>(emb, offsets, eids, src, w, out, N);
    } else {
        hipMemsetAsync(d_out, 0, (size_t)out_size * sizeof(float), stream);
        long long total = (long long)E * 16;
        int grid = (int)((total + block - 1) / block);
        lightgcn_scatter<<<grid, block, 0, stream>>>(emb, w, src, dst, out, E);
        int gridN = (N + 3) / 4;
        lightgcn_normalize<<<gridN, 256, 0, stream>>>(out, N);
    }
}

// Round 10
// 313.971 us; speedup vs baseline: 1.2124x; 1.2000x over previous
//
#include <hip/hip_runtime.h>
#include <hip/hip_fp16.h>

#define EMB_D 64
#define SB 1024   // scan block size

// ===========================================================================
// Tier A: fp16 emb + packed (src17|w15) plain CSR.
//   fused cast+hist -> 3-phase scan (cursors in place) -> bucket (8 node-span
//   groups, strict 1-XCD region ownership [R7-proven], local cursor atomics,
//   packed payload) -> gather (quarter-wave, 2-deep pipeline, fused L2 norm)
// Tier B: Round-7 fp32 pipeline (proven 335 us). Tier C: atomic scatter.
// ===========================================================================

__device__ __forceinline__ float h15_to_float(unsigned int bits) {
    return __half2float(__ushort_as_half((unsigned short)bits));
}

// --- Tier A: fused cast(emb fp32->fp16) + histogram over dst --------------
#define CAST_BLOCKS 256
__global__ void fused_cast_hist(const float2* __restrict__ embin,
                                __half2* __restrict__ emb16, int n2,
                                const int* __restrict__ dst,
                                int* __restrict__ counts, int E) {
    if (blockIdx.x < CAST_BLOCKS) {
        int i = blockIdx.x * blockDim.x + threadIdx.x;
        int st = CAST_BLOCKS * blockDim.x;
        for (; i < n2; i += st)
            emb16[i] = __float22half2_rn(embin[i]);
    } else {
        int i = (blockIdx.x - CAST_BLOCKS) * blockDim.x + threadIdx.x;
        int st = (gridDim.x - CAST_BLOCKS) * blockDim.x;
        for (; i < E; i += st)
            atomicAdd(&counts[dst[i]], 1);
    }
}

// --- shared 3-phase scan (length M) --------------------------------------
__global__ void scan_reduce(const int* __restrict__ counts,
                            int* __restrict__ partial, int M) {
    __shared__ int wsum[16];
    const int tid = threadIdx.x, lane = tid & 63, wid = tid >> 6;
    int i = blockIdx.x * SB + tid;
    int v = (i < M) ? counts[i] : 0;
    #pragma unroll
    for (int off = 32; off > 0; off >>= 1)
        v += __shfl_xor(v, off, 64);
    if (lane == 0) wsum[wid] = v;
    __syncthreads();
    if (tid == 0) {
        int s = 0;
        #pragma unroll
        for (int k = 0; k < 16; ++k) s += wsum[k];
        partial[blockIdx.x] = s;
    }
}

__global__ void scan_partials(const int* __restrict__ partial,
                              int* __restrict__ blockoff,
                              int* __restrict__ offsets, int numB, int M) {
    __shared__ int wsum[16];
    __shared__ int wpre[16];
    const int tid = threadIdx.x, lane = tid & 63, wid = tid >> 6;
    int v = (tid < numB) ? partial[tid] : 0;
    int x = v;
    #pragma unroll
    for (int off = 1; off < 64; off <<= 1) {
        int t = __shfl_up(x, off, 64);
        if (lane >= off) x += t;
    }
    if (lane == 63) wsum[wid] = x;
    __syncthreads();
    if (wid == 0) {
        int s = (lane < 16) ? wsum[lane] : 0;
        #pragma unroll
        for (int off = 1; off < 16; off <<= 1) {
            int t = __shfl_up(s, off, 64);
            if (lane >= off) s += t;
        }
        if (lane < 16) wpre[lane] = s;
    }
    __syncthreads();
    int excl = ((wid > 0) ? wpre[wid - 1] : 0) + (x - v);
    if (tid < numB) blockoff[tid] = excl;
    if (tid == 0) offsets[M] = wpre[15];   // grand total = E
}

// writes offsets[i]; optionally mirrors excl into cursors (may alias counts)
__global__ void scan_apply(const int* __restrict__ counts,
                           const int* __restrict__ blockoff,
                           int* __restrict__ offsets,
                           int* __restrict__ cursors, int M) {
    __shared__ int wsum[16];
    __shared__ int wpre[16];
    const int tid = threadIdx.x, lane = tid & 63, wid = tid >> 6;
    int i = blockIdx.x * SB + tid;
    int v = (i < M) ? counts[i] : 0;
    int x = v;
    #pragma unroll
    for (int off = 1; off < 64; off <<= 1) {
        int t = __shfl_up(x, off, 64);
        if (lane >= off) x += t;
    }
    if (lane == 63) wsum[wid] = x;
    __syncthreads();
    if (wid == 0) {
        int s = (lane < 16) ? wsum[lane] : 0;
        #pragma unroll
        for (int off = 1; off < 16; off <<= 1) {
            int t = __shfl_up(s, off, 64);
            if (lane >= off) s += t;
        }
        if (lane < 16) wpre[lane] = s;
    }
    __syncthreads();
    int excl = blockoff[blockIdx.x] + ((wid > 0) ? wpre[wid - 1] : 0) + (x - v);
    if (i < M) {
        offsets[i] = excl;
        if (cursors) cursors[i] = excl;
    }
}

// --- Tier A: bucket scatter, 8 node-span groups, strict 1-XCD ownership ---
// Group g = blockIdx&7 owns node span [g*span,(g+1)*span): its store region
// and its cursor slice are touched ONLY by blocks with blockIdx%8==g (one
// XCD under round-robin dispatch) -> full-line write combining + local-L2
// cursor atomics. (R9 showed even 2-XCD sharing destroys combining.)
__global__ void bucketS_kernel(const int* __restrict__ src,
                               const int* __restrict__ dst,
                               const float* __restrict__ w,
                               int* __restrict__ cursors,
                               unsigned int* __restrict__ packed,
                               int E, int span, int N) {
    int g = blockIdx.x & 7;
    int b = blockIdx.x >> 3;
    int lo = g * span;
    int hi = min(lo + span, N);
    int stride = (gridDim.x >> 3) * blockDim.x;
    for (int i = b * blockDim.x + threadIdx.x; i < E; i += stride) {
        int v = dst[i];
        if (v >= lo && v < hi) {
            int slot = atomicAdd(&cursors[v], 1);
            unsigned int wb = __half_as_ushort(__float2half_rn(w[i]));
            packed[slot] = ((unsigned int)src[i] << 15) | (wb & 0x7FFFu);
        }
    }
}

// --- Tier A: fp16 gather, quarter-wave per edge, 2-deep pipeline ---------
// Wave = 64 lanes: quarter q = lane>>4 processes edge j+q; lane ql = lane&15
// owns dims [4ql,4ql+4) via one 8B uint2 (= 4 halves). Invalid lanes use the
// sentinel pk=0 (row 0, weight +0) so loads stay unpredicated.
__global__ __launch_bounds__(256) void gatherS_kernel(
        const uint2* __restrict__ emb16,       // row v = 16 x uint2 (128 B)
        const int* __restrict__ offsets,       // [N+1]
        const unsigned int* __restrict__ packed,
        float* __restrict__ out, int N) {
    int node = blockIdx.x * 4 + (threadIdx.x >> 6);
    int lane = threadIdx.x & 63;
    if (node >= N) return;
    int q  = lane >> 4;
    int ql = lane & 15;

    int beg = offsets[node];
    int end = offsets[node + 1];

    float a0 = 0.f, a1 = 0.f, a2 = 0.f, a3 = 0.f;

    int idx0 = beg + q;
    unsigned int pk0 = (idx0 < end) ? packed[idx0] : 0u;
    uint2 r0 = emb16[(size_t)(pk0 >> 15) * 16 + ql];

    for (int j = beg; j < end; j += 4) {
        int idx1 = idx0 + 4;
        unsigned int pk1 = (idx1 < end) ? packed[idx1] : 0u;
        uint2 r1 = emb16[(size_t)(pk1 >> 15) * 16 + ql];  // next in flight

        float wt = h15_to_float(pk0 & 0x7FFFu);
        float2 x01 = __half22float2(*reinterpret_cast<__half2*>(&r0.x));
        float2 x23 = __half22float2(*reinterpret_cast<__half2*>(&r0.y));
        a0 = fmaf(x01.x, wt, a0);
        a1 = fmaf(x01.y, wt, a1);
        a2 = fmaf(x23.x, wt, a2);
        a3 = fmaf(x23.y, wt, a3);

        pk0 = pk1; r0 = r1; idx0 = idx1;
    }

    // merge the 4 quarter-wave partials (same dims, different edges)
    a0 += __shfl_xor(a0, 16, 64); a0 += __shfl_xor(a0, 32, 64);
    a1 += __shfl_xor(a1, 16, 64); a1 += __shfl_xor(a1, 32, 64);
    a2 += __shfl_xor(a2, 16, 64); a2 += __shfl_xor(a2, 32, 64);
    a3 += __shfl_xor(a3, 16, 64); a3 += __shfl_xor(a3, 32, 64);

    float ss = a0 * a0 + a1 * a1 + a2 * a2 + a3 * a3;
    #pragma unroll
    for (int off = 8; off > 0; off >>= 1)
        ss += __shfl_xor(ss, off, 64);
    float scale = 1.0f / fmaxf(sqrtf(ss), 1e-12f);

    if (q == 0) {
        float4 o = make_float4(a0 * scale, a1 * scale, a2 * scale, a3 * scale);
        reinterpret_cast<float4*>(out + (size_t)node * EMB_D)[ql] = o;
    }
}

// ===========================================================================
// Tier B: Round-7 pipeline (fp32, eids CSR) — proven 335 us.
// ===========================================================================
__global__ void hist_kernel(const int* __restrict__ dst, int* __restrict__ counts,
                            int* __restrict__ ranks, int E) {
    int i = blockIdx.x * blockDim.x + threadIdx.x;
    int stride = gridDim.x * blockDim.x;
    for (; i < E; i += stride)
        ranks[i] = atomicAdd(&counts[dst[i]], 1);
}

__global__ void bucket_kernel(const int* __restrict__ dst,
                              const int* __restrict__ ranks,
                              const int* __restrict__ offsets,
                              int* __restrict__ eids, int E, int span) {
    int xcd = blockIdx.x & 7;
    int g   = blockIdx.x >> 3;
    int lo = xcd * span;
    int hi = lo + span;
    int stride = (gridDim.x >> 3) * blockDim.x;
    for (int i = g * blockDim.x + threadIdx.x; i < E; i += stride) {
        int v = dst[i];
        if (v >= lo && v < hi)
            eids[offsets[v] + ranks[i]] = i;
    }
}

__global__ __launch_bounds__(256) void gather_norm_kernel(
        const float* __restrict__ emb,
        const int* __restrict__ offsets,
        const int* __restrict__ eids,
        const int* __restrict__ src,
        const float* __restrict__ w,
        float* __restrict__ out, int N) {
    int node = blockIdx.x * 4 + (threadIdx.x >> 6);
    int lane = threadIdx.x & 63;
    if (node >= N) return;

    int beg = offsets[node];
    int end = offsets[node + 1];

    float a0 = 0.f, a1 = 0.f, a2 = 0.f, a3 = 0.f;
    int j = beg;
    for (; j + 4 <= end; j += 4) {
        int e0 = eids[j + 0], e1 = eids[j + 1];
        int e2 = eids[j + 2], e3 = eids[j + 3];
        int s0 = src[e0], s1 = src[e1], s2 = src[e2], s3 = src[e3];
        float w0 = w[e0], w1 = w[e1], w2 = w[e2], w3 = w[e3];
        a0 = fmaf(emb[(size_t)s0 * EMB_D + lane], w0, a0);
        a1 = fmaf(emb[(size_t)s1 * EMB_D + lane], w1, a1);
        a2 = fmaf(emb[(size_t)s2 * EMB_D + lane], w2, a2);
        a3 = fmaf(emb[(size_t)s3 * EMB_D + lane], w3, a3);
    }
    for (; j < end; ++j) {
        int e = eids[j];
        a0 = fmaf(emb[(size_t)src[e] * EMB_D + lane], w[e], a0);
    }
    float acc = (a0 + a1) + (a2 + a3);

    float ss = acc * acc;
    #pragma unroll
    for (int off = 32; off > 0; off >>= 1)
        ss += __shfl_xor(ss, off, 64);
    float scale = 1.0f / fmaxf(sqrtf(ss), 1e-12f);
    out[(size_t)node * EMB_D + lane] = acc * scale;
}

// ===========================================================================
// Tier C: atomic scatter fallback.
// ===========================================================================
__global__ void lightgcn_scatter(const float* __restrict__ emb,
                                 const float* __restrict__ w,
                                 const int* __restrict__ src,
                                 const int* __restrict__ dst,
                                 float* __restrict__ h, int E) {
    long long t = (long long)blockIdx.x * blockDim.x + threadIdx.x;
    int e = (int)(t >> 4);
    int d = (int)(t & 15) << 2;
    if (e >= E) return;
    int s = src[e]; int v = dst[e]; float wt = w[e];
    const float4 m = *reinterpret_cast<const float4*>(emb + (size_t)s * EMB_D + d);
    float* o = h + (size_t)v * EMB_D + d;
    unsafeAtomicAdd(o + 0, m.x * wt);
    unsafeAtomicAdd(o + 1, m.y * wt);
    unsafeAtomicAdd(o + 2, m.z * wt);
    unsafeAtomicAdd(o + 3, m.w * wt);
}

__global__ void lightgcn_normalize(float* __restrict__ h, int N) {
    int row = blockIdx.x * (blockDim.x >> 6) + (threadIdx.x >> 6);
    int lane = threadIdx.x & 63;
    if (row >= N) return;
    float x = h[(size_t)row * EMB_D + lane];
    float ss = x * x;
    #pragma unroll
    for (int off = 32; off > 0; off >>= 1)
        ss += __shfl_xor(ss, off, 64);
    h[(size_t)row * EMB_D + lane] = x / fmaxf(sqrtf(ss), 1e-12f);
}

extern "C" void kernel_launch(void* const* d_in, const int* in_sizes, int n_in,
                              void* d_out, int out_size, void* d_ws, size_t ws_size,
                              hipStream_t stream) {
    const float* emb = (const float*)d_in[0];   // [N, 64] fp32
    const float* w   = (const float*)d_in[1];   // [E] fp32
    const int*   src = (const int*)d_in[2];     // [E] int32
    const int*   dst = (const int*)d_in[3];     // [E] int32
    float* out = (float*)d_out;

    const int N = in_sizes[0] / EMB_D;
    const int E = in_sizes[1];
    const int block = 256;

    // ---- Tier A workspace: counts[N] | offsets[N+1] | partial | blockoff |
    //      packed[E] | pad16 | emb16[N*64 halves]  (~17.6 MB) ----
    const int numBA = (N + SB - 1) / SB;
    size_t intsA = (size_t)(2 * N + 1 + 2 * numBA) + E;
    size_t embOff = (intsA * sizeof(int) + 15) & ~(size_t)15;
    size_t neededA = embOff + (size_t)N * EMB_D * sizeof(__half);

    // ---- Tier B workspace ----
    const int numB7 = (N + SB - 1) / SB;
    size_t needed7 = (size_t)(2 * N + 1 + 2 * numB7 + 2 * E) * sizeof(int);

    if (ws_size >= neededA && numBA <= 1024) {
        int* counts   = (int*)d_ws;          // N (becomes cursors after scan)
        int* offsets  = counts + N;          // N+1
        int* partial  = offsets + N + 1;
        int* blockoff = partial + numBA;
        unsigned int* packed = (unsigned int*)(blockoff + numBA);   // E
        __half2* emb16 = (__half2*)((char*)d_ws + embOff);

        hipMemsetAsync(counts, 0, (size_t)N * sizeof(int), stream);

        int n2 = N * (EMB_D / 2);
        fused_cast_hist<<<CAST_BLOCKS + 1024, block, 0, stream>>>(
            (const float2*)emb, emb16, n2, dst, counts, E);

        scan_reduce<<<numBA, SB, 0, stream>>>(counts, partial, N);
        scan_partials<<<1, SB, 0, stream>>>(partial, blockoff, offsets, numBA, N);
        // mirrors exclusive sums into counts (in place) as bucket cursors
        scan_apply<<<numBA, SB, 0, stream>>>(counts, blockoff, offsets, counts, N);

        int span = (N + 7) / 8;
        bucketS_kernel<<<8 * 256, block, 0, stream>>>(src, dst, w, counts,
                                                      packed, E, span, N);

        int gridN = (N + 3) / 4;
        gatherS_kernel<<<gridN, 256, 0, stream>>>((const uint2*)emb16, offsets,
                                                  packed, out, N);
    } else if (ws_size >= needed7 && numB7 <= 1024) {
        int* counts   = (int*)d_ws;
        int* offsets  = counts + N;
        int* partial  = offsets + N + 1;
        int* blockoff = partial + numB7;
        int* ranks    = blockoff + numB7;
        int* eids     = ranks + E;

        hipMemsetAsync(counts, 0, (size_t)N * sizeof(int), stream);

        int gridE = (E + block - 1) / block;
        hist_kernel<<<gridE, block, 0, stream>>>(dst, counts, ranks, E);
        scan_reduce<<<numB7, SB, 0, stream>>>(counts, partial, N);
        scan_partials<<<1, SB, 0, stream>>>(partial, blockoff, offsets, numB7, N);
        scan_apply<<<numB7, SB, 0, stream>>>(counts, blockoff, offsets, nullptr, N);

        int span = (N + 7) / 8;
        bucket_kernel<<<8 * 256, block, 0, stream>>>(dst, ranks, offsets, eids, E, span);

        int gridN = (N + 3) / 4;
        gather_norm_kernel<<<gridN, 256, 0, stream>>>(emb, offsets, eids, src, w, out, N);
    } else {
        hipMemsetAsync(d_out, 0, (size_t)out_size * sizeof(float), stream);
        long long total = (long long)E * 16;
        int grid = (int)((total + block - 1) / block);
        lightgcn_scatter<<<grid, block, 0, stream>>>(emb, w, src, dst, out, E);
        int gridN = (N + 3) / 4;
        lightgcn_normalize<<<gridN, 256, 0, stream>>>(out, N);
    }
}

// Round 11
// 308.294 us; speedup vs baseline: 1.2348x; 1.0184x over previous
//
#include <hip/hip_runtime.h>
#include <hip/hip_fp16.h>

#define EMB_D 64
#define SB 1024   // scan block size

// ===========================================================================
// Tier A: fp16 emb + packed (src17|w15) plain CSR.
//   fused cast + 8-way-replicated hist (per-XCD count slices, no cross-XCD
//   atomic line bouncing) -> 3-phase scan folding the 8 slices -> bucket
//   (8 node-span groups, strict 1-XCD region ownership, local cursor
//   atomics) -> gather (quarter-wave, 2-deep pipeline, fused L2 norm)
// Tier B: Round-7 fp32 pipeline (proven 335 us). Tier C: atomic scatter.
// ===========================================================================

__device__ __forceinline__ float h15_to_float(unsigned int bits) {
    return __half2float(__ushort_as_half((unsigned short)bits));
}

// --- Tier A: fused cast(emb fp32->fp16) + replicated histogram ------------
// Hist blocks write counts8[(blockIdx&7)*N + v]: each slice is touched by
// one blockIdx%8 class -> one XCD (R7/R10-proven heuristic) -> atomics stay
// in that XCD's L2, no coherence bouncing. CAST_BLOCKS is divisible by 8 so
// hist blocks keep a uniform %8 distribution.
#define CAST_BLOCKS 256
__global__ void fused_cast_hist(const float2* __restrict__ embin,
                                __half2* __restrict__ emb16, int n2,
                                const int* __restrict__ dst,
                                int* __restrict__ counts8, int E, int N) {
    if (blockIdx.x < CAST_BLOCKS) {
        int i = blockIdx.x * blockDim.x + threadIdx.x;
        int st = CAST_BLOCKS * blockDim.x;
        for (; i < n2; i += st)
            emb16[i] = __float22half2_rn(embin[i]);
    } else {
        int* mycounts = counts8 + (size_t)(blockIdx.x & 7) * N;
        int i = (blockIdx.x - CAST_BLOCKS) * blockDim.x + threadIdx.x;
        int st = (gridDim.x - CAST_BLOCKS) * blockDim.x;
        for (; i < E; i += st)
            atomicAdd(&mycounts[dst[i]], 1);
    }
}

// --- 3-phase scan over node counts, folding the 8 replicated slices -------
__device__ __forceinline__ int fold_counts(const int* counts8, int i, int N) {
    int v = 0;
    #pragma unroll
    for (int g = 0; g < 8; ++g) v += counts8[(size_t)g * N + i];
    return v;
}

__global__ void scan_reduce(const int* __restrict__ counts8,
                            int* __restrict__ partial, int N) {
    __shared__ int wsum[16];
    const int tid = threadIdx.x, lane = tid & 63, wid = tid >> 6;
    int i = blockIdx.x * SB + tid;
    int v = (i < N) ? fold_counts(counts8, i, N) : 0;
    #pragma unroll
    for (int off = 32; off > 0; off >>= 1)
        v += __shfl_xor(v, off, 64);
    if (lane == 0) wsum[wid] = v;
    __syncthreads();
    if (tid == 0) {
        int s = 0;
        #pragma unroll
        for (int k = 0; k < 16; ++k) s += wsum[k];
        partial[blockIdx.x] = s;
    }
}

__global__ void scan_partials(const int* __restrict__ partial,
                              int* __restrict__ blockoff,
                              int* __restrict__ offsets, int numB, int M) {
    __shared__ int wsum[16];
    __shared__ int wpre[16];
    const int tid = threadIdx.x, lane = tid & 63, wid = tid >> 6;
    int v = (tid < numB) ? partial[tid] : 0;
    int x = v;
    #pragma unroll
    for (int off = 1; off < 64; off <<= 1) {
        int t = __shfl_up(x, off, 64);
        if (lane >= off) x += t;
    }
    if (lane == 63) wsum[wid] = x;
    __syncthreads();
    if (wid == 0) {
        int s = (lane < 16) ? wsum[lane] : 0;
        #pragma unroll
        for (int off = 1; off < 16; off <<= 1) {
            int t = __shfl_up(s, off, 64);
            if (lane >= off) s += t;
        }
        if (lane < 16) wpre[lane] = s;
    }
    __syncthreads();
    int excl = ((wid > 0) ? wpre[wid - 1] : 0) + (x - v);
    if (tid < numB) blockoff[tid] = excl;
    if (tid == 0) offsets[M] = wpre[15];   // grand total = E
}

// writes offsets[i] and mirrors the exclusive sum into cursors[i]
__global__ void scan_apply(const int* __restrict__ counts8,
                           const int* __restrict__ blockoff,
                           int* __restrict__ offsets,
                           int* __restrict__ cursors, int N) {
    __shared__ int wsum[16];
    __shared__ int wpre[16];
    const int tid = threadIdx.x, lane = tid & 63, wid = tid >> 6;
    int i = blockIdx.x * SB + tid;
    int v = (i < N) ? fold_counts(counts8, i, N) : 0;
    int x = v;
    #pragma unroll
    for (int off = 1; off < 64; off <<= 1) {
        int t = __shfl_up(x, off, 64);
        if (lane >= off) x += t;
    }
    if (lane == 63) wsum[wid] = x;
    __syncthreads();
    if (wid == 0) {
        int s = (lane < 16) ? wsum[lane] : 0;
        #pragma unroll
        for (int off = 1; off < 16; off <<= 1) {
            int t = __shfl_up(s, off, 64);
            if (lane >= off) s += t;
        }
        if (lane < 16) wpre[lane] = s;
    }
    __syncthreads();
    int excl = blockoff[blockIdx.x] + ((wid > 0) ? wpre[wid - 1] : 0) + (x - v);
    if (i < N) {
        offsets[i] = excl;
        cursors[i] = excl;
    }
}

// --- Tier A: bucket scatter, 8 node-span groups, strict 1-XCD ownership ---
// Group g = blockIdx&7 owns node span [g*span,(g+1)*span): its store region
// and its cursor slice are touched ONLY by blocks with blockIdx%8==g (one
// XCD under round-robin dispatch) -> full-line write combining + local-L2
// cursor atomics. (R9: even 2-XCD sharing destroys combining.)
__global__ void bucketS_kernel(const int* __restrict__ src,
                               const int* __restrict__ dst,
                               const float* __restrict__ w,
                               int* __restrict__ cursors,
                               unsigned int* __restrict__ packed,
                               int E, int span, int N) {
    int g = blockIdx.x & 7;
    int b = blockIdx.x >> 3;
    int lo = g * span;
    int hi = min(lo + span, N);
    int stride = (gridDim.x >> 3) * blockDim.x;
    for (int i = b * blockDim.x + threadIdx.x; i < E; i += stride) {
        int v = dst[i];
        if (v >= lo && v < hi) {
            int slot = atomicAdd(&cursors[v], 1);
            unsigned int wb = __half_as_ushort(__float2half_rn(w[i]));
            packed[slot] = ((unsigned int)src[i] << 15) | (wb & 0x7FFFu);
        }
    }
}

// --- Tier A: fp16 gather, quarter-wave per edge, 2-deep pipeline ---------
__global__ __launch_bounds__(256) void gatherS_kernel(
        const uint2* __restrict__ emb16,       // row v = 16 x uint2 (128 B)
        const int* __restrict__ offsets,       // [N+1]
        const unsigned int* __restrict__ packed,
        float* __restrict__ out, int N) {
    int node = blockIdx.x * 4 + (threadIdx.x >> 6);
    int lane = threadIdx.x & 63;
    if (node >= N) return;
    int q  = lane >> 4;
    int ql = lane & 15;

    int beg = offsets[node];
    int end = offsets[node + 1];

    float a0 = 0.f, a1 = 0.f, a2 = 0.f, a3 = 0.f;

    int idx0 = beg + q;
    unsigned int pk0 = (idx0 < end) ? packed[idx0] : 0u;
    uint2 r0 = emb16[(size_t)(pk0 >> 15) * 16 + ql];

    for (int j = beg; j < end; j += 4) {
        int idx1 = idx0 + 4;
        unsigned int pk1 = (idx1 < end) ? packed[idx1] : 0u;
        uint2 r1 = emb16[(size_t)(pk1 >> 15) * 16 + ql];  // next in flight

        float wt = h15_to_float(pk0 & 0x7FFFu);
        float2 x01 = __half22float2(*reinterpret_cast<__half2*>(&r0.x));
        float2 x23 = __half22float2(*reinterpret_cast<__half2*>(&r0.y));
        a0 = fmaf(x01.x, wt, a0);
        a1 = fmaf(x01.y, wt, a1);
        a2 = fmaf(x23.x, wt, a2);
        a3 = fmaf(x23.y, wt, a3);

        pk0 = pk1; r0 = r1; idx0 = idx1;
    }

    a0 += __shfl_xor(a0, 16, 64); a0 += __shfl_xor(a0, 32, 64);
    a1 += __shfl_xor(a1, 16, 64); a1 += __shfl_xor(a1, 32, 64);
    a2 += __shfl_xor(a2, 16, 64); a2 += __shfl_xor(a2, 32, 64);
    a3 += __shfl_xor(a3, 16, 64); a3 += __shfl_xor(a3, 32, 64);

    float ss = a0 * a0 + a1 * a1 + a2 * a2 + a3 * a3;
    #pragma unroll
    for (int off = 8; off > 0; off >>= 1)
        ss += __shfl_xor(ss, off, 64);
    float scale = 1.0f / fmaxf(sqrtf(ss), 1e-12f);

    if (q == 0) {
        float4 o = make_float4(a0 * scale, a1 * scale, a2 * scale, a3 * scale);
        reinterpret_cast<float4*>(out + (size_t)node * EMB_D)[ql] = o;
    }
}

// ===========================================================================
// Tier B: Round-7 pipeline (fp32, eids CSR) — proven 335 us.
// ===========================================================================
__global__ void hist_kernel(const int* __restrict__ dst, int* __restrict__ counts,
                            int* __restrict__ ranks, int E) {
    int i = blockIdx.x * blockDim.x + threadIdx.x;
    int stride = gridDim.x * blockDim.x;
    for (; i < E; i += stride)
        ranks[i] = atomicAdd(&counts[dst[i]], 1);
}

__global__ void scan_reduceB(const int* __restrict__ counts,
                             int* __restrict__ partial, int M) {
    __shared__ int wsum[16];
    const int tid = threadIdx.x, lane = tid & 63, wid = tid >> 6;
    int i = blockIdx.x * SB + tid;
    int v = (i < M) ? counts[i] : 0;
    #pragma unroll
    for (int off = 32; off > 0; off >>= 1)
        v += __shfl_xor(v, off, 64);
    if (lane == 0) wsum[wid] = v;
    __syncthreads();
    if (tid == 0) {
        int s = 0;
        #pragma unroll
        for (int k = 0; k < 16; ++k) s += wsum[k];
        partial[blockIdx.x] = s;
    }
}

__global__ void scan_applyB(const int* __restrict__ counts,
                            const int* __restrict__ blockoff,
                            int* __restrict__ offsets, int M) {
    __shared__ int wsum[16];
    __shared__ int wpre[16];
    const int tid = threadIdx.x, lane = tid & 63, wid = tid >> 6;
    int i = blockIdx.x * SB + tid;
    int v = (i < M) ? counts[i] : 0;
    int x = v;
    #pragma unroll
    for (int off = 1; off < 64; off <<= 1) {
        int t = __shfl_up(x, off, 64);
        if (lane >= off) x += t;
    }
    if (lane == 63) wsum[wid] = x;
    __syncthreads();
    if (wid == 0) {
        int s = (lane < 16) ? wsum[lane] : 0;
        #pragma unroll
        for (int off = 1; off < 16; off <<= 1) {
            int t = __shfl_up(s, off, 64);
            if (lane >= off) s += t;
        }
        if (lane < 16) wpre[lane] = s;
    }
    __syncthreads();
    int excl = blockoff[blockIdx.x] + ((wid > 0) ? wpre[wid - 1] : 0) + (x - v);
    if (i < M) offsets[i] = excl;
}

__global__ void bucket_kernel(const int* __restrict__ dst,
                              const int* __restrict__ ranks,
                              const int* __restrict__ offsets,
                              int* __restrict__ eids, int E, int span) {
    int xcd = blockIdx.x & 7;
    int g   = blockIdx.x >> 3;
    int lo = xcd * span;
    int hi = lo + span;
    int stride = (gridDim.x >> 3) * blockDim.x;
    for (int i = g * blockDim.x + threadIdx.x; i < E; i += stride) {
        int v = dst[i];
        if (v >= lo && v < hi)
            eids[offsets[v] + ranks[i]] = i;
    }
}

__global__ __launch_bounds__(256) void gather_norm_kernel(
        const float* __restrict__ emb,
        const int* __restrict__ offsets,
        const int* __restrict__ eids,
        const int* __restrict__ src,
        const float* __restrict__ w,
        float* __restrict__ out, int N) {
    int node = blockIdx.x * 4 + (threadIdx.x >> 6);
    int lane = threadIdx.x & 63;
    if (node >= N) return;

    int beg = offsets[node];
    int end = offsets[node + 1];

    float a0 = 0.f, a1 = 0.f, a2 = 0.f, a3 = 0.f;
    int j = beg;
    for (; j + 4 <= end; j += 4) {
        int e0 = eids[j + 0], e1 = eids[j + 1];
        int e2 = eids[j + 2], e3 = eids[j + 3];
        int s0 = src[e0], s1 = src[e1], s2 = src[e2], s3 = src[e3];
        float w0 = w[e0], w1 = w[e1], w2 = w[e2], w3 = w[e3];
        a0 = fmaf(emb[(size_t)s0 * EMB_D + lane], w0, a0);
        a1 = fmaf(emb[(size_t)s1 * EMB_D + lane], w1, a1);
        a2 = fmaf(emb[(size_t)s2 * EMB_D + lane], w2, a2);
        a3 = fmaf(emb[(size_t)s3 * EMB_D + lane], w3, a3);
    }
    for (; j < end; ++j) {
        int e = eids[j];
        a0 = fmaf(emb[(size_t)src[e] * EMB_D + lane], w[e], a0);
    }
    float acc = (a0 + a1) + (a2 + a3);

    float ss = acc * acc;
    #pragma unroll
    for (int off = 32; off > 0; off >>= 1)
        ss += __shfl_xor(ss, off, 64);
    float scale = 1.0f / fmaxf(sqrtf(ss), 1e-12f);
    out[(size_t)node * EMB_D + lane] = acc * scale;
}

// ===========================================================================
// Tier C: atomic scatter fallback.
// ===========================================================================
__global__ void lightgcn_scatter(const float* __restrict__ emb,
                                 const float* __restrict__ w,
                                 const int* __restrict__ src,
                                 const int* __restrict__ dst,
                                 float* __restrict__ h, int E) {
    long long t = (long long)blockIdx.x * blockDim.x + threadIdx.x;
    int e = (int)(t >> 4);
    int d = (int)(t & 15) << 2;
    if (e >= E) return;
    int s = src[e]; int v = dst[e]; float wt = w[e];
    const float4 m = *reinterpret_cast<const float4*>(emb + (size_t)s * EMB_D + d);
    float* o = h + (size_t)v * EMB_D + d;
    unsafeAtomicAdd(o + 0, m.x * wt);
    unsafeAtomicAdd(o + 1, m.y * wt);
    unsafeAtomicAdd(o + 2, m.z * wt);
    unsafeAtomicAdd(o + 3, m.w * wt);
}

__global__ void lightgcn_normalize(float* __restrict__ h, int N) {
    int row = blockIdx.x * (blockDim.x >> 6) + (threadIdx.x >> 6);
    int lane = threadIdx.x & 63;
    if (row >= N) return;
    float x = h[(size_t)row * EMB_D + lane];
    float ss = x * x;
    #pragma unroll
    for (int off = 32; off > 0; off >>= 1)
        ss += __shfl_xor(ss, off, 64);
    h[(size_t)row * EMB_D + lane] = x / fmaxf(sqrtf(ss), 1e-12f);
}

extern "C" void kernel_launch(void* const* d_in, const int* in_sizes, int n_in,
                              void* d_out, int out_size, void* d_ws, size_t ws_size,
                              hipStream_t stream) {
    const float* emb = (const float*)d_in[0];   // [N, 64] fp32
    const float* w   = (const float*)d_in[1];   // [E] fp32
    const int*   src = (const int*)d_in[2];     // [E] int32
    const int*   dst = (const int*)d_in[3];     // [E] int32
    float* out = (float*)d_out;

    const int N = in_sizes[0] / EMB_D;
    const int E = in_sizes[1];
    const int block = 256;

    // ---- Tier A workspace: counts8[8N] | cursors[N] | offsets[N+1] |
    //      partial | blockoff | packed[E] | pad16 | emb16  (~20.2 MB) ----
    const int numBA = (N + SB - 1) / SB;
    size_t intsA = (size_t)(9 * N + N + 1 + 2 * numBA) + E;
    size_t embOff = (intsA * sizeof(int) + 15) & ~(size_t)15;
    size_t neededA = embOff + (size_t)N * EMB_D * sizeof(__half);

    // ---- Tier B workspace ----
    const int numB7 = (N + SB - 1) / SB;
    size_t needed7 = (size_t)(2 * N + 1 + 2 * numB7 + 2 * E) * sizeof(int);

    if (ws_size >= neededA && numBA <= 1024) {
        int* counts8  = (int*)d_ws;          // 8N
        int* cursors  = counts8 + (size_t)8 * N;  // N
        int* offsets  = cursors + N;         // N+1
        int* partial  = offsets + N + 1;
        int* blockoff = partial + numBA;
        unsigned int* packed = (unsigned int*)(blockoff + numBA);   // E
        __half2* emb16 = (__half2*)((char*)d_ws + embOff);

        hipMemsetAsync(counts8, 0, (size_t)8 * N * sizeof(int), stream);

        int n2 = N * (EMB_D / 2);
        fused_cast_hist<<<CAST_BLOCKS + 1024, block, 0, stream>>>(
            (const float2*)emb, emb16, n2, dst, counts8, E, N);

        scan_reduce<<<numBA, SB, 0, stream>>>(counts8, partial, N);
        scan_partials<<<1, SB, 0, stream>>>(partial, blockoff, offsets, numBA, N);
        scan_apply<<<numBA, SB, 0, stream>>>(counts8, blockoff, offsets, cursors, N);

        int span = (N + 7) / 8;
        bucketS_kernel<<<8 * 256, block, 0, stream>>>(src, dst, w, cursors,
                                                      packed, E, span, N);

        int gridN = (N + 3) / 4;
        gatherS_kernel<<<gridN, 256, 0, stream>>>((const uint2*)emb16, offsets,
                                                  packed, out, N);
    } else if (ws_size >= needed7 && numB7 <= 1024) {
        int* counts   = (int*)d_ws;
        int* offsets  = counts + N;
        int* partial  = offsets + N + 1;
        int* blockoff = partial + numB7;
        int* ranks    = blockoff + numB7;
        int* eids     = ranks + E;

        hipMemsetAsync(counts, 0, (size_t)N * sizeof(int), stream);

        int gridE = (E + block - 1) / block;
        hist_kernel<<<gridE, block, 0, stream>>>(dst, counts, ranks, E);
        scan_reduceB<<<numB7, SB, 0, stream>>>(counts, partial, N);
        scan_partials<<<1, SB, 0, stream>>>(partial, blockoff, offsets, numB7, N);
        scan_applyB<<<numB7, SB, 0, stream>>>(counts, blockoff, offsets, N);

        int span = (N + 7) / 8;
        bucket_kernel<<<8 * 256, block, 0, stream>>>(dst, ranks, offsets, eids, E, span);

        int gridN = (N + 3) / 4;
        gather_norm_kernel<<<gridN, 256, 0, stream>>>(emb, offsets, eids, src, w, out, N);
    } else {
        hipMemsetAsync(d_out, 0, (size_t)out_size * sizeof(float), stream);
        long long total = (long long)E * 16;
        int grid = (int)((total + block - 1) / block);
        lightgcn_scatter<<<grid, block, 0, stream>>>(emb, w, src, dst, out, E);
        int gridN = (N + 3) / 4;
        lightgcn_normalize<<<gridN, 256, 0, stream>>>(out, N);
    }
}